// Round 8
// baseline (398.468 us; speedup 1.0000x reference)
//
#include <hip/hip_runtime.h>
#include <hip/hip_fp16.h>

#define B_ 64
#define F_ 4
#define M_ 4096
#define D_ 1024
#define W_ 16      // u64 words per D bits
#define CW_ 64     // u64 words per M bits
#define NITER 15
#define NBLK_LOOP 128
#define FPAD 16    // ints per flag (64B line)

typedef _Float16 f16;
typedef _Float16 f16x8 __attribute__((ext_vector_type(8)));
typedef float f32x4 __attribute__((ext_vector_type(4)));
typedef unsigned int u32;
typedef unsigned short u16;
typedef unsigned long long u64;

#define LD_AG(p)     __hip_atomic_load((p), __ATOMIC_RELAXED, __HIP_MEMORY_SCOPE_AGENT)
#define ST_AG(p, v)  __hip_atomic_store((p), (v), __ATOMIC_RELAXED, __HIP_MEMORY_SCOPE_AGENT)

// ---- device-global scratch (rebuilt every call) ----
__device__ __align__(16) u64 g_cbBits[F_ * M_ * W_];    // 2 MB: cb packed along d
__device__ __align__(16) u64 g_colBits[F_ * D_ * CW_];  // 2 MB: cb packed along m
__device__ __align__(16) f16 g_G[F_ * D_ * D_];         // 8 MB: G = cb^T cb (even ints <=4096, exact fp16)
__device__ __align__(16) u64 g_inBits[B_ * W_];
__device__ __align__(16) u64 g_est[2][B_ * F_ * W_];    // ping-pong packed estimates
__device__ int g_done[NITER][NBLK_LOOP * FPAD];         // flag-array barrier (one line per block)
__device__ int g_mismatch[16];
__device__ int g_iters;
__device__ int g_conv;

__device__ __forceinline__ u32 nib16(u32 x) {
    x &= 0x0F0F0F0Fu;
    x = (x | (x >> 4)) & 0x00FF00FFu;
    x = (x | (x >> 8)) & 0x0000FFFFu;
    return x;
}

// ---- bit-pack via nibble-LDS + zero barrier flags ----
__global__ __launch_bounds__(256) void k_pack(const float* __restrict__ inp,
                                              const float* __restrict__ est0,
                                              const float* __restrict__ cb) {
    __shared__ unsigned char nib[4096];   // 4 waves x 4 rows x 256 nibbles
    int blk = blockIdx.x, tid = threadIdx.x;
    int wv = tid >> 6, lane = tid & 63;
    const float* src; u64* dst; int r0;
    if (blk < 1024)      { src = cb;   dst = g_cbBits; r0 = blk * 16; }
    else if (blk < 1040) { src = est0; dst = g_est[0]; r0 = (blk - 1024) * 16; }
    else if (blk < 1044) { src = inp;  dst = g_inBits; r0 = (blk - 1040) * 16; }
    else if (blk == 1044) {
        if (tid < 16) g_mismatch[tid] = 0;
        else if (tid == 16) g_iters = 0;
        else if (tid == 17) g_conv = 0;
        return;
    } else {                               // blocks 1045.. : zero g_done
        int idx = (blk - 1045) * 256 + tid;
        if (idx < NITER * NBLK_LOOP * FPAD) ((int*)g_done)[idx] = 0;
        return;
    }
    int rw = r0 + wv * 4;
    unsigned char* mynib = nib + wv * 1024;
    #pragma unroll
    for (int rr = 0; rr < 4; rr++) {
        const float4* s4 = (const float4*)(src + (size_t)(rw + rr) * D_);
        #pragma unroll
        for (int it = 0; it < 4; it++) {
            float4 v = s4[it * 64 + lane];
            u32 n = (__float_as_uint(v.x) >> 31)
                  | (((__float_as_uint(v.y) >> 31)) << 1)
                  | (((__float_as_uint(v.z) >> 31)) << 2)
                  | (((__float_as_uint(v.w) >> 31)) << 3);
            mynib[rr * 256 + it * 64 + lane] = (unsigned char)n;
        }
    }
    uint4 q = *(const uint4*)(mynib + (lane >> 4) * 256 + (lane & 15) * 16);
    u32 w0 = nib16(q.x), w1 = nib16(q.y), w2 = nib16(q.z), w3 = nib16(q.w);
    u64 word = (u64)(w0 | (w1 << 16)) | ((u64)(w2 | (w3 << 16)) << 32);
    dst[(size_t)(rw + (lane >> 4)) * W_ + (lane & 15)] = word;
}

// ---- 64x64 bit-transpose: cbBits[m][wd] -> colBits[d][wm] ----
__global__ __launch_bounds__(256) void k_bitT() {
    int tid = threadIdx.x, wv = tid >> 6, lane = tid & 63;
    int tbase = (blockIdx.x * 4 + wv) * 4;
    for (int q = 0; q < 4; q++) {
        int task = tbase + q;
        int mt = task & 63;
        int wd = (task >> 6) & 15;
        int f  = task >> 10;
        u64 row = g_cbBits[((size_t)(f * M_ + mt * 64 + lane)) * W_ + wd];
        u64 myout = 0;
        #pragma unroll
        for (int j = 0; j < 64; j++) {
            u64 t = __ballot((row >> j) & 1ULL);
            if (lane == j) myout = t;
        }
        g_colBits[((size_t)(f * D_ + wd * 64 + lane)) * CW_ + mt] = myout;
    }
}

// ---- G = cb^T cb, symmetric: only t1<=t2 pairs; mirror via LDS transpose ----
__global__ __launch_bounds__(256) void k_G() {
    int blk = blockIdx.x;                  // 544 = f(4) x 136 pairs
    int f = blk / 136;
    int pi = blk % 136;
    int t1 = 0;
    while (pi >= 16 - t1) { pi -= 16 - t1; t1++; }
    int t2 = t1 + pi;
    __shared__ u64 L1T[64][64];            // [w][d_loc]
    __shared__ u64 L2T[64][64];
    int tid = threadIdx.x;
    int wv = tid >> 6, lane = tid & 63;
    for (int it = 0; it < 16; it++) {
        int w = it * 4 + wv;
        L1T[w][lane] = g_colBits[((size_t)(f * D_ + t1 * 64 + lane)) * CW_ + w];
        L2T[w][lane] = g_colBits[((size_t)(f * D_ + t2 * 64 + lane)) * CW_ + w];
    }
    __syncthreads();
    int g1 = tid >> 4, g2 = tid & 15;
    int p[4][4] = {};
    for (int w = 0; w < 64; w++) {
        u64 a0 = L1T[w][g1], a1 = L1T[w][g1 + 16], a2 = L1T[w][g1 + 32], a3 = L1T[w][g1 + 48];
        u64 b0 = L2T[w][g2], b1 = L2T[w][g2 + 16], b2 = L2T[w][g2 + 32], b3 = L2T[w][g2 + 48];
        p[0][0] += __popcll(a0 ^ b0); p[0][1] += __popcll(a0 ^ b1);
        p[0][2] += __popcll(a0 ^ b2); p[0][3] += __popcll(a0 ^ b3);
        p[1][0] += __popcll(a1 ^ b0); p[1][1] += __popcll(a1 ^ b1);
        p[1][2] += __popcll(a1 ^ b2); p[1][3] += __popcll(a1 ^ b3);
        p[2][0] += __popcll(a2 ^ b0); p[2][1] += __popcll(a2 ^ b1);
        p[2][2] += __popcll(a2 ^ b2); p[2][3] += __popcll(a2 ^ b3);
        p[3][0] += __popcll(a3 ^ b0); p[3][1] += __popcll(a3 ^ b1);
        p[3][2] += __popcll(a3 ^ b2); p[3][3] += __popcll(a3 ^ b3);
    }
    #pragma unroll
    for (int i = 0; i < 4; i++) {
        int d1 = t1 * 64 + g1 + 16 * i;
        #pragma unroll
        for (int j = 0; j < 4; j++) {
            int d2 = t2 * 64 + g2 + 16 * j;
            g_G[((size_t)(f * D_ + d1)) * D_ + d2] = (f16)(M_ - 2 * p[i][j]);
        }
    }
    if (t1 == t2) return;
    __syncthreads();
    f16* Lt = (f16*)L1T;
    #pragma unroll
    for (int i = 0; i < 4; i++)
        #pragma unroll
        for (int j = 0; j < 4; j++)
            Lt[(g2 + 16 * j) * 72 + (g1 + 16 * i)] = (f16)(M_ - 2 * p[i][j]);
    __syncthreads();
    int r = tid >> 2, c0 = (tid & 3) * 16;
    const uint4* s = (const uint4*)&Lt[r * 72 + c0];
    uint4 v0 = s[0], v1 = s[1];
    uint4* dsto = (uint4*)&g_G[((size_t)(f * D_ + t2 * 64 + r)) * D_ + t1 * 64 + c0];
    dsto[0] = v0; dsto[1] = v1;
}

__device__ __forceinline__ u32 pairval(u32 bits, int i) {
    // two bits -> two fp16: 0x3C00 (+1) / 0xBC00 (-1)
    return 0x3C003C00u | (((bits >> i) & 1u) << 15) | (((bits >> (i + 1)) & 1u) << 31);
}

// ---- fused 15-iter loop + cleanup; flag-array barrier (no RMW contention) ----
// 128 blocks = f(4) x dg(32); block owns d-cols [dg*32, dg*32+32).
__global__ __launch_bounds__(256) void k_loop(float* __restrict__ out) {
    int blk = blockIdx.x;
    int f = blk & 3, dg = blk >> 2;
    int tid = threadIdx.x;
    int wv = tid >> 6, lane = tid & 63;
    __shared__ u64 neL[64][17];
    __shared__ __align__(16) char ldsB[32 * 2048];  // 32 G-rows x 1024 k, XOR-swizzled
    __shared__ int red[256];
    {   // stage this block's G slice ONCE
        const char* gsrc = (const char*)(g_G + ((size_t)(f * D_ + dg * 32)) * D_);
        for (int i = tid; i < 4096; i += 256) {
            int row = i >> 7, col = i & 127;
            uint4 v = *(const uint4*)(gsrc + (size_t)row * 2048 + col * 16);
            *(uint4*)(ldsB + row * 2048 + ((col * 16) ^ ((row & 7) << 4))) = v;
        }
    }
    const unsigned char* neB = (const unsigned char*)neL;
    int dd = lane & 15, gg = lane >> 4;
    int aBase = (wv * 16 + dd) * 136 + gg;
    for (int t = 0; t < NITER; t++) {
        const u64* rb = g_est[t & 1];
        const u32* rb32 = (const u32*)rb;
        u32* wb32 = (u32*)g_est[(t + 1) & 1];
        if (blk == 0 && tid == 0) {                 // fold previous iter's convergence
            if (t > 0 && LD_AG(&g_mismatch[t - 1]) == 0) g_conv = 1;
            if (!g_conv) g_iters++;
        }
        for (int idx = tid; idx < 1024; idx += 256) {   // ne = in * prod_{j!=f} est_j
            int b = idx >> 4, w = idx & 15;
            u64 e0 = LD_AG(&rb[(b * 4 + 0) * W_ + w]);
            u64 e1 = LD_AG(&rb[(b * 4 + 1) * W_ + w]);
            u64 e2 = LD_AG(&rb[(b * 4 + 2) * W_ + w]);
            u64 e3 = LD_AG(&rb[(b * 4 + 3) * W_ + w]);
            u64 x = g_inBits[b * W_ + w] ^ e0 ^ e1 ^ e2 ^ e3;
            u64 ef = (f == 0) ? e0 : (f == 1) ? e1 : (f == 2) ? e2 : e3;
            neL[b][w] = x ^ ef;
        }
        __syncthreads();
        f32x4 acc[2][2] = {};
        #pragma unroll
        for (int c = 0; c < 32; c++) {
            u32 bits = neB[aBase + c * 4];
            f16x8 a;
            ((u32*)&a)[0] = pairval(bits, 0);
            ((u32*)&a)[1] = pairval(bits, 2);
            ((u32*)&a)[2] = pairval(bits, 4);
            ((u32*)&a)[3] = pairval(bits, 6);
            #pragma unroll
            for (int ct = 0; ct < 2; ct++) {
                int rowB = ct * 16 + dd;
                f16x8 bf = *(const f16x8*)(ldsB + rowB * 2048 +
                                           ((c * 64 + gg * 16) ^ ((rowB & 7) << 4)));
                acc[ct][c & 1] =
                    __builtin_amdgcn_mfma_f32_16x16x32_f16(a, bf, acc[ct][c & 1], 0, 0, 0);
            }
        }
        u64 msk[2][4];
        #pragma unroll
        for (int ct = 0; ct < 2; ct++)
            #pragma unroll
            for (int j = 0; j < 4; j++) {
                float v = acc[ct][0][j] + acc[ct][1][j];    // exact int
                msk[ct][j] = __ballot(v < 0.0f);
            }
        int mm = 0;
        if (dd == 0) {                              // writer lanes: one u32 per b
            #pragma unroll
            for (int j = 0; j < 4; j++) {
                int b = wv * 16 + gg * 4 + j;
                u32 nv = (u32)((msk[0][j] >> (gg * 16)) & 0xFFFFu)
                       | ((u32)((msk[1][j] >> (gg * 16)) & 0xFFFFu) << 16);
                int oi = (b * 4 + f) * 32 + dg;
                u32 ov = LD_AG(&rb32[oi]);
                if (ov != nv) mm = 1;
                ST_AG(&wb32[oi], nv);
            }
        }
        u64 anym = __ballot(mm != 0);
        if (lane == 0 && anym)
            __hip_atomic_fetch_or(&g_mismatch[t], 1, __ATOMIC_RELAXED, __HIP_MEMORY_SCOPE_AGENT);
        __syncthreads();                            // all waves' est stores drained (vmcnt 0)
        if (tid == 0)
            __hip_atomic_store(&g_done[t][blk * FPAD], 1,
                               __ATOMIC_RELEASE, __HIP_MEMORY_SCOPE_AGENT);
        if (tid < NBLK_LOOP) {                      // each thread polls ONE distinct line
            while (__hip_atomic_load(&g_done[t][tid * FPAD],
                                     __ATOMIC_ACQUIRE, __HIP_MEMORY_SCOPE_AGENT) == 0)
                __builtin_amdgcn_s_sleep(1);
        }
        __syncthreads();
    }
    // ---- final cleanup: 2 (b,f) tasks per block ----
    const u64* eb_g = g_est[NITER & 1];
    if (blk == 0 && tid == 0) {
        int convf = g_conv;
        if (LD_AG(&g_mismatch[NITER - 1]) == 0) convf = 1;
        out[256 + 262144] = (float)g_iters;
        out[256 + 262144 + 1] = (float)convf;
    }
    for (int s = 0; s < 2; s++) {
        int task = blk * 2 + s;
        int bb = task >> 2, ff = task & 3;
        for (int j = 0; j < 4; j++) {
            int d = j * 256 + tid;
            u64 w = LD_AG(&eb_g[(size_t)(bb * 4 + ff) * W_ + (d >> 6)]);
            out[256 + ((size_t)(bb * 4 + ff)) * D_ + d] = ((w >> (d & 63)) & 1) ? -1.0f : 1.0f;
        }
        u64 eb[W_];
        #pragma unroll
        for (int w = 0; w < W_; w++) eb[w] = LD_AG(&eb_g[(size_t)(bb * 4 + ff) * W_ + w]);
        int bestKey = -1;
        for (int j = 0; j < 16; j++) {
            int m = j * 256 + tid;
            int p = 0;
            #pragma unroll
            for (int w = 0; w < W_; w++)
                p += __popcll(eb[w] ^ g_cbBits[((size_t)(ff * M_ + m)) * W_ + w]);
            int sv = D_ - 2 * p;
            int a = sv < 0 ? -sv : sv;
            int key = (a << 12) | (4095 - m);   // max |sim|, then min m
            if (key > bestKey) bestKey = key;
        }
        red[tid] = bestKey;
        __syncthreads();
        for (int off = 128; off > 0; off >>= 1) {
            if (tid < off) red[tid] = max(red[tid], red[tid + off]);
            __syncthreads();
        }
        if (tid == 0) out[bb * 4 + ff] = (float)(4095 - (red[0] & 0xFFF));
        __syncthreads();
    }
}

extern "C" void kernel_launch(void* const* d_in, const int* in_sizes, int n_in,
                              void* d_out, int out_size, void* d_ws, size_t ws_size,
                              hipStream_t stream) {
    (void)d_ws; (void)ws_size;
    const float* inp  = (const float*)d_in[0];
    const float* est0 = (const float*)d_in[1];
    const float* cb   = (const float*)d_in[2];
    float* out = (float*)d_out;

    int flagInts = NITER * NBLK_LOOP * FPAD;
    int zeroBlks = (flagInts + 255) / 256;          // 120
    k_pack<<<1045 + zeroBlks, 256, 0, stream>>>(inp, est0, cb);
    k_bitT<<<256, 256, 0, stream>>>();
    k_G<<<544, 256, 0, stream>>>();
    k_loop<<<NBLK_LOOP, 256, 0, stream>>>(out);
}

// Round 9
// 317.231 us; speedup vs baseline: 1.2561x; 1.2561x over previous
//
#include <hip/hip_runtime.h>
#include <hip/hip_fp16.h>

#define B_ 64
#define F_ 4
#define M_ 4096
#define D_ 1024
#define W_ 16      // u64 words per D bits
#define CW_ 64     // u64 words per M bits
#define NITER 15
#define NBLK 64    // loop blocks: f(4) x dg(16)
#define FPAD 16    // ints per flag line (64B)

typedef _Float16 f16;
typedef _Float16 f16x8 __attribute__((ext_vector_type(8)));
typedef float f32x4 __attribute__((ext_vector_type(4)));
typedef unsigned int u32;
typedef unsigned short u16;
typedef unsigned long long u64;

#define LD_AG(p)     __hip_atomic_load((p), __ATOMIC_RELAXED, __HIP_MEMORY_SCOPE_AGENT)
#define ST_AG(p, v)  __hip_atomic_store((p), (v), __ATOMIC_RELAXED, __HIP_MEMORY_SCOPE_AGENT)

// ---- device-global scratch (rebuilt every call) ----
__device__ __align__(16) u64 g_cbBits[F_ * M_ * W_];    // 2 MB: cb packed along d
__device__ __align__(16) u64 g_colBits[F_ * D_ * CW_];  // 2 MB: cb packed along m
__device__ __align__(16) f16 g_G[F_ * D_ * D_];         // 8 MB: G = cb^T cb (even ints <=4096, exact fp16)
__device__ __align__(16) u64 g_inBits[B_ * W_];
__device__ __align__(16) u64 g_est[2][B_ * F_ * W_];    // ping-pong packed estimates
__device__ int g_done[NITER][NBLK * FPAD];              // barrier flags, one line per block
__device__ int g_mism[NITER][NBLK * FPAD];              // mismatch flags, one line per block

__device__ __forceinline__ u32 nib16(u32 x) {
    x &= 0x0F0F0F0Fu;
    x = (x | (x >> 4)) & 0x00FF00FFu;
    x = (x | (x >> 8)) & 0x0000FFFFu;
    return x;
}

// ---- bit-pack via nibble-LDS + zero flag arrays ----
__global__ __launch_bounds__(256) void k_pack(const float* __restrict__ inp,
                                              const float* __restrict__ est0,
                                              const float* __restrict__ cb) {
    __shared__ unsigned char nib[4096];   // 4 waves x 4 rows x 256 nibbles
    int blk = blockIdx.x, tid = threadIdx.x;
    int wv = tid >> 6, lane = tid & 63;
    const float* src; u64* dst; int r0;
    if (blk < 1024)      { src = cb;   dst = g_cbBits; r0 = blk * 16; }
    else if (blk < 1040) { src = est0; dst = g_est[0]; r0 = (blk - 1024) * 16; }
    else if (blk < 1044) { src = inp;  dst = g_inBits; r0 = (blk - 1040) * 16; }
    else {                                 // zero g_done + g_mism
        int idx = (blk - 1044) * 256 + tid;
        const int n = NITER * NBLK * FPAD;
        if (idx < n) ((int*)g_done)[idx] = 0;
        else if (idx < 2 * n) ((int*)g_mism)[idx - n] = 0;
        return;
    }
    int rw = r0 + wv * 4;
    unsigned char* mynib = nib + wv * 1024;
    #pragma unroll
    for (int rr = 0; rr < 4; rr++) {
        const float4* s4 = (const float4*)(src + (size_t)(rw + rr) * D_);
        #pragma unroll
        for (int it = 0; it < 4; it++) {
            float4 v = s4[it * 64 + lane];
            u32 n = (__float_as_uint(v.x) >> 31)
                  | (((__float_as_uint(v.y) >> 31)) << 1)
                  | (((__float_as_uint(v.z) >> 31)) << 2)
                  | (((__float_as_uint(v.w) >> 31)) << 3);
            mynib[rr * 256 + it * 64 + lane] = (unsigned char)n;
        }
    }
    uint4 q = *(const uint4*)(mynib + (lane >> 4) * 256 + (lane & 15) * 16);
    u32 w0 = nib16(q.x), w1 = nib16(q.y), w2 = nib16(q.z), w3 = nib16(q.w);
    u64 word = (u64)(w0 | (w1 << 16)) | ((u64)(w2 | (w3 << 16)) << 32);
    dst[(size_t)(rw + (lane >> 4)) * W_ + (lane & 15)] = word;
}

// ---- 64x64 bit-transpose: cbBits[m][wd] -> colBits[d][wm] ----
__global__ __launch_bounds__(256) void k_bitT() {
    int tid = threadIdx.x, wv = tid >> 6, lane = tid & 63;
    int tbase = (blockIdx.x * 4 + wv) * 4;
    for (int q = 0; q < 4; q++) {
        int task = tbase + q;
        int mt = task & 63;
        int wd = (task >> 6) & 15;
        int f  = task >> 10;
        u64 row = g_cbBits[((size_t)(f * M_ + mt * 64 + lane)) * W_ + wd];
        u64 myout = 0;
        #pragma unroll
        for (int j = 0; j < 64; j++) {
            u64 t = __ballot((row >> j) & 1ULL);
            if (lane == j) myout = t;
        }
        g_colBits[((size_t)(f * D_ + wd * 64 + lane)) * CW_ + mt] = myout;
    }
}

// ---- G = cb^T cb, symmetric: only t1<=t2 pairs; mirror via LDS transpose ----
__global__ __launch_bounds__(256) void k_G() {
    int blk = blockIdx.x;                  // 544 = f(4) x 136 pairs
    int f = blk / 136;
    int pi = blk % 136;
    int t1 = 0;
    while (pi >= 16 - t1) { pi -= 16 - t1; t1++; }
    int t2 = t1 + pi;
    __shared__ u64 L1T[64][64];            // [w][d_loc]
    __shared__ u64 L2T[64][64];
    int tid = threadIdx.x;
    int wv = tid >> 6, lane = tid & 63;
    for (int it = 0; it < 16; it++) {
        int w = it * 4 + wv;
        L1T[w][lane] = g_colBits[((size_t)(f * D_ + t1 * 64 + lane)) * CW_ + w];
        L2T[w][lane] = g_colBits[((size_t)(f * D_ + t2 * 64 + lane)) * CW_ + w];
    }
    __syncthreads();
    int g1 = tid >> 4, g2 = tid & 15;
    int p[4][4] = {};
    for (int w = 0; w < 64; w++) {
        u64 a0 = L1T[w][g1], a1 = L1T[w][g1 + 16], a2 = L1T[w][g1 + 32], a3 = L1T[w][g1 + 48];
        u64 b0 = L2T[w][g2], b1 = L2T[w][g2 + 16], b2 = L2T[w][g2 + 32], b3 = L2T[w][g2 + 48];
        p[0][0] += __popcll(a0 ^ b0); p[0][1] += __popcll(a0 ^ b1);
        p[0][2] += __popcll(a0 ^ b2); p[0][3] += __popcll(a0 ^ b3);
        p[1][0] += __popcll(a1 ^ b0); p[1][1] += __popcll(a1 ^ b1);
        p[1][2] += __popcll(a1 ^ b2); p[1][3] += __popcll(a1 ^ b3);
        p[2][0] += __popcll(a2 ^ b0); p[2][1] += __popcll(a2 ^ b1);
        p[2][2] += __popcll(a2 ^ b2); p[2][3] += __popcll(a2 ^ b3);
        p[3][0] += __popcll(a3 ^ b0); p[3][1] += __popcll(a3 ^ b1);
        p[3][2] += __popcll(a3 ^ b2); p[3][3] += __popcll(a3 ^ b3);
    }
    #pragma unroll
    for (int i = 0; i < 4; i++) {
        int d1 = t1 * 64 + g1 + 16 * i;
        #pragma unroll
        for (int j = 0; j < 4; j++) {
            int d2 = t2 * 64 + g2 + 16 * j;
            g_G[((size_t)(f * D_ + d1)) * D_ + d2] = (f16)(M_ - 2 * p[i][j]);
        }
    }
    if (t1 == t2) return;
    __syncthreads();
    f16* Lt = (f16*)L1T;
    #pragma unroll
    for (int i = 0; i < 4; i++)
        #pragma unroll
        for (int j = 0; j < 4; j++)
            Lt[(g2 + 16 * j) * 72 + (g1 + 16 * i)] = (f16)(M_ - 2 * p[i][j]);
    __syncthreads();
    int r = tid >> 2, c0 = (tid & 3) * 16;
    const uint4* s = (const uint4*)&Lt[r * 72 + c0];
    uint4 v0 = s[0], v1 = s[1];
    uint4* dsto = (uint4*)&g_G[((size_t)(f * D_ + t2 * 64 + r)) * D_ + t1 * 64 + c0];
    dsto[0] = v0; dsto[1] = v1;
}

__device__ __forceinline__ u32 pairval(u32 bits, int i) {
    // two bits -> two fp16: 0x3C00 (+1) / 0xBC00 (-1)
    return 0x3C003C00u | (((bits >> i) & 1u) << 15) | (((bits >> (i + 1)) & 1u) << 31);
}

// ---- fused 15-iter loop + cleanup; RMW-free flag barrier, no cache-op fences ----
// 64 blocks = f(4) x dg(16); block owns d-cols [dg*64, dg*64+64) = one u64 est word.
__global__ __launch_bounds__(256) void k_loop(float* __restrict__ out) {
    int blk = blockIdx.x;
    int f = blk & 3, dg = blk >> 2;
    int tid = threadIdx.x;
    int wv = tid >> 6, lane = tid & 63;
    __shared__ u64 neL[64][17];
    __shared__ __align__(16) char ldsB[64 * 2048];  // 64 G-rows x 1024 k, XOR-swizzled
    __shared__ int red[256];
    {   // stage this block's G slice ONCE (128 KB)
        const char* gsrc = (const char*)(g_G + ((size_t)(f * D_ + dg * 64)) * D_);
        for (int i = tid; i < 8192; i += 256) {
            int row = i >> 7, col = i & 127;
            uint4 v = *(const uint4*)(gsrc + (size_t)row * 2048 + col * 16);
            *(uint4*)(ldsB + row * 2048 + ((col * 16) ^ ((row & 7) << 4))) = v;
        }
    }
    const unsigned char* neB = (const unsigned char*)neL;
    int dd = lane & 15, gg = lane >> 4;
    int aBase = (wv * 16 + dd) * 136 + gg;
    int iters = 0, conv = 0;                        // live in block0's registers
    for (int t = 0; t < NITER; t++) {
        const u64* rb = g_est[t & 1];
        u64* wb = g_est[(t + 1) & 1];
        if (blk == 0) {                             // fold previous iter's convergence
            if (t > 0 && tid < NBLK) {
                const int* mp = &g_mism[t - 1][tid * FPAD];
                int v = LD_AG(&mp[0]) | LD_AG(&mp[1]) | LD_AG(&mp[2]) | LD_AG(&mp[3]);
                u64 any = __ballot(v != 0);
                if (tid == 0 && any == 0) conv = 1;
            }
            if (tid == 0 && !conv) iters++;
        }
        for (int idx = tid; idx < 1024; idx += 256) {   // ne = in * prod_{j!=f} est_j
            int b = idx >> 4, w = idx & 15;
            u64 e0 = LD_AG(&rb[(b * 4 + 0) * W_ + w]);
            u64 e1 = LD_AG(&rb[(b * 4 + 1) * W_ + w]);
            u64 e2 = LD_AG(&rb[(b * 4 + 2) * W_ + w]);
            u64 e3 = LD_AG(&rb[(b * 4 + 3) * W_ + w]);
            u64 x = g_inBits[b * W_ + w] ^ e0 ^ e1 ^ e2 ^ e3;
            u64 ef = (f == 0) ? e0 : (f == 1) ? e1 : (f == 2) ? e2 : e3;
            neL[b][w] = x ^ ef;
        }
        __syncthreads();
        f32x4 acc[4][2] = {};
        #pragma unroll
        for (int c = 0; c < 32; c++) {
            u32 bits = neB[aBase + c * 4];
            f16x8 a;
            ((u32*)&a)[0] = pairval(bits, 0);
            ((u32*)&a)[1] = pairval(bits, 2);
            ((u32*)&a)[2] = pairval(bits, 4);
            ((u32*)&a)[3] = pairval(bits, 6);
            #pragma unroll
            for (int ct = 0; ct < 4; ct++) {
                int rowB = ct * 16 + dd;
                f16x8 bf = *(const f16x8*)(ldsB + rowB * 2048 +
                                           ((c * 64 + gg * 16) ^ ((rowB & 7) << 4)));
                acc[ct][c & 1] =
                    __builtin_amdgcn_mfma_f32_16x16x32_f16(a, bf, acc[ct][c & 1], 0, 0, 0);
            }
        }
        u64 msk[4][4];
        #pragma unroll
        for (int ct = 0; ct < 4; ct++)
            #pragma unroll
            for (int j = 0; j < 4; j++) {
                float v = acc[ct][0][j] + acc[ct][1][j];    // exact int
                msk[ct][j] = __ballot(v < 0.0f);
            }
        int mm = 0;
        if (dd == 0) {                              // writer lanes: one u64 per b
            #pragma unroll
            for (int j = 0; j < 4; j++) {
                int b = wv * 16 + gg * 4 + j;
                u64 nv = ((msk[0][j] >> (gg * 16)) & 0xFFFFu)
                       | (((msk[1][j] >> (gg * 16)) & 0xFFFFu) << 16)
                       | (((msk[2][j] >> (gg * 16)) & 0xFFFFu) << 32)
                       | (((msk[3][j] >> (gg * 16)) & 0xFFFFu) << 48);
                size_t oi = (size_t)(b * 4 + f) * W_ + dg;
                u64 ov = LD_AG(&rb[oi]);
                if (ov != nv) mm = 1;
                ST_AG(&wb[oi], nv);
            }
        }
        u64 anym = __ballot(mm != 0);
        if (lane == 0 && anym)
            ST_AG(&g_mism[t][blk * FPAD + wv], 1);  // own line, no RMW
        __syncthreads();                            // vmcnt(0) drain of ALL waves' stores
        if (tid == 0)
            ST_AG(&g_done[t][blk * FPAD], 1);
        if (tid < NBLK) {                           // each thread polls one distinct line
            while (LD_AG(&g_done[t][tid * FPAD]) == 0)
                __builtin_amdgcn_s_sleep(1);
        }
        __syncthreads();
    }
    // ---- final cleanup: 4 (b,f) tasks per block ----
    const u64* eb_g = g_est[NITER & 1];
    if (blk == 0) {
        if (tid < NBLK) {
            const int* mp = &g_mism[NITER - 1][tid * FPAD];
            int v = LD_AG(&mp[0]) | LD_AG(&mp[1]) | LD_AG(&mp[2]) | LD_AG(&mp[3]);
            u64 any = __ballot(v != 0);
            if (tid == 0) {
                if (any == 0) conv = 1;
                out[256 + 262144] = (float)iters;
                out[256 + 262144 + 1] = (float)conv;
            }
        }
    }
    for (int s = 0; s < 4; s++) {
        int task = blk * 4 + s;
        int bb = task >> 2, ff = task & 3;
        for (int j = 0; j < 4; j++) {
            int d = j * 256 + tid;
            u64 w = LD_AG(&eb_g[(size_t)(bb * 4 + ff) * W_ + (d >> 6)]);
            out[256 + ((size_t)(bb * 4 + ff)) * D_ + d] = ((w >> (d & 63)) & 1) ? -1.0f : 1.0f;
        }
        u64 eb[W_];
        #pragma unroll
        for (int w = 0; w < W_; w++) eb[w] = LD_AG(&eb_g[(size_t)(bb * 4 + ff) * W_ + w]);
        int bestKey = -1;
        for (int j = 0; j < 16; j++) {
            int m = j * 256 + tid;
            int p = 0;
            #pragma unroll
            for (int w = 0; w < W_; w++)
                p += __popcll(eb[w] ^ g_cbBits[((size_t)(ff * M_ + m)) * W_ + w]);
            int sv = D_ - 2 * p;
            int a = sv < 0 ? -sv : sv;
            int key = (a << 12) | (4095 - m);   // max |sim|, then min m
            if (key > bestKey) bestKey = key;
        }
        red[tid] = bestKey;
        __syncthreads();
        for (int off = 128; off > 0; off >>= 1) {
            if (tid < off) red[tid] = max(red[tid], red[tid + off]);
            __syncthreads();
        }
        if (tid == 0) out[bb * 4 + ff] = (float)(4095 - (red[0] & 0xFFF));
        __syncthreads();
    }
}

extern "C" void kernel_launch(void* const* d_in, const int* in_sizes, int n_in,
                              void* d_out, int out_size, void* d_ws, size_t ws_size,
                              hipStream_t stream) {
    (void)d_ws; (void)ws_size;
    const float* inp  = (const float*)d_in[0];
    const float* est0 = (const float*)d_in[1];
    const float* cb   = (const float*)d_in[2];
    float* out = (float*)d_out;

    int flagInts = 2 * NITER * NBLK * FPAD;
    int zeroBlks = (flagInts + 255) / 256;          // 120
    k_pack<<<1044 + zeroBlks, 256, 0, stream>>>(inp, est0, cb);
    k_bitT<<<256, 256, 0, stream>>>();
    k_G<<<544, 256, 0, stream>>>();
    k_loop<<<NBLK, 256, 0, stream>>>(out);
}

// Round 10
// 299.698 us; speedup vs baseline: 1.3296x; 1.0585x over previous
//
#include <hip/hip_runtime.h>
#include <hip/hip_fp16.h>

#define B_ 64
#define F_ 4
#define M_ 4096
#define D_ 1024
#define W_ 16      // u64 words per D bits
#define CW_ 64     // u64 words per M bits
#define NITER 15
#define NBLK 64    // loop blocks: f(4) x dg(16)
#define FPAD 16    // ints per flag line (64B)

typedef _Float16 f16;
typedef _Float16 f16x8 __attribute__((ext_vector_type(8)));
typedef float f32x4 __attribute__((ext_vector_type(4)));
typedef unsigned int u32;
typedef unsigned short u16;
typedef unsigned long long u64;

#define LD_AG(p)     __hip_atomic_load((p), __ATOMIC_RELAXED, __HIP_MEMORY_SCOPE_AGENT)
#define ST_AG(p, v)  __hip_atomic_store((p), (v), __ATOMIC_RELAXED, __HIP_MEMORY_SCOPE_AGENT)

// ---- device-global scratch (rebuilt every call) ----
__device__ __align__(16) u64 g_cbBits[F_ * M_ * W_];    // 2 MB: cb packed along d
__device__ __align__(16) u64 g_colBits[F_ * D_ * CW_];  // 2 MB: cb packed along m
__device__ __align__(16) f16 g_G[F_ * D_ * D_];         // 8 MB: G = cb^T cb (even ints <=4096, exact fp16)
__device__ __align__(16) u64 g_inBits[B_ * W_];
__device__ __align__(16) u64 g_est[2][B_ * F_ * W_];    // ping-pong packed estimates
__device__ int g_done[NITER][NBLK * FPAD];              // barrier flags, one line per block
__device__ int g_mism[NITER][NBLK * FPAD];              // mismatch flags, one line per block

__device__ __forceinline__ u32 nib16(u32 x) {
    x &= 0x0F0F0F0Fu;
    x = (x | (x >> 4)) & 0x00FF00FFu;
    x = (x | (x >> 8)) & 0x0000FFFFu;
    return x;
}

// ---- bit-pack via nibble-LDS + zero flag arrays ----
__global__ __launch_bounds__(256) void k_pack(const float* __restrict__ inp,
                                              const float* __restrict__ est0,
                                              const float* __restrict__ cb) {
    __shared__ unsigned char nib[4096];   // 4 waves x 4 rows x 256 nibbles
    int blk = blockIdx.x, tid = threadIdx.x;
    int wv = tid >> 6, lane = tid & 63;
    const float* src; u64* dst; int r0;
    if (blk < 1024)      { src = cb;   dst = g_cbBits; r0 = blk * 16; }
    else if (blk < 1040) { src = est0; dst = g_est[0]; r0 = (blk - 1024) * 16; }
    else if (blk < 1044) { src = inp;  dst = g_inBits; r0 = (blk - 1040) * 16; }
    else {                                 // zero g_done + g_mism
        int idx = (blk - 1044) * 256 + tid;
        const int n = NITER * NBLK * FPAD;
        if (idx < n) ((int*)g_done)[idx] = 0;
        else if (idx < 2 * n) ((int*)g_mism)[idx - n] = 0;
        return;
    }
    int rw = r0 + wv * 4;
    unsigned char* mynib = nib + wv * 1024;
    #pragma unroll
    for (int rr = 0; rr < 4; rr++) {
        const float4* s4 = (const float4*)(src + (size_t)(rw + rr) * D_);
        #pragma unroll
        for (int it = 0; it < 4; it++) {
            float4 v = s4[it * 64 + lane];
            u32 n = (__float_as_uint(v.x) >> 31)
                  | (((__float_as_uint(v.y) >> 31)) << 1)
                  | (((__float_as_uint(v.z) >> 31)) << 2)
                  | (((__float_as_uint(v.w) >> 31)) << 3);
            mynib[rr * 256 + it * 64 + lane] = (unsigned char)n;
        }
    }
    uint4 q = *(const uint4*)(mynib + (lane >> 4) * 256 + (lane & 15) * 16);
    u32 w0 = nib16(q.x), w1 = nib16(q.y), w2 = nib16(q.z), w3 = nib16(q.w);
    u64 word = (u64)(w0 | (w1 << 16)) | ((u64)(w2 | (w3 << 16)) << 32);
    dst[(size_t)(rw + (lane >> 4)) * W_ + (lane & 15)] = word;
}

// ---- 64x64 bit-transpose: cbBits[m][wd] -> colBits[d][wm] ----
__global__ __launch_bounds__(256) void k_bitT() {
    int tid = threadIdx.x, wv = tid >> 6, lane = tid & 63;
    int tbase = (blockIdx.x * 4 + wv) * 4;
    for (int q = 0; q < 4; q++) {
        int task = tbase + q;
        int mt = task & 63;
        int wd = (task >> 6) & 15;
        int f  = task >> 10;
        u64 row = g_cbBits[((size_t)(f * M_ + mt * 64 + lane)) * W_ + wd];
        u64 myout = 0;
        #pragma unroll
        for (int j = 0; j < 64; j++) {
            u64 t = __ballot((row >> j) & 1ULL);
            if (lane == j) myout = t;
        }
        g_colBits[((size_t)(f * D_ + wd * 64 + lane)) * CW_ + mt] = myout;
    }
}

// ---- G = cb^T cb, symmetric: only t1<=t2 pairs; mirror via LDS transpose ----
__global__ __launch_bounds__(256) void k_G() {
    int blk = blockIdx.x;                  // 544 = f(4) x 136 pairs
    int f = blk / 136;
    int pi = blk % 136;
    int t1 = 0;
    while (pi >= 16 - t1) { pi -= 16 - t1; t1++; }
    int t2 = t1 + pi;
    __shared__ u64 L1T[64][64];            // [w][d_loc]
    __shared__ u64 L2T[64][64];
    int tid = threadIdx.x;
    int wv = tid >> 6, lane = tid & 63;
    for (int it = 0; it < 16; it++) {
        int w = it * 4 + wv;
        L1T[w][lane] = g_colBits[((size_t)(f * D_ + t1 * 64 + lane)) * CW_ + w];
        L2T[w][lane] = g_colBits[((size_t)(f * D_ + t2 * 64 + lane)) * CW_ + w];
    }
    __syncthreads();
    int g1 = tid >> 4, g2 = tid & 15;
    int p[4][4] = {};
    for (int w = 0; w < 64; w++) {
        u64 a0 = L1T[w][g1], a1 = L1T[w][g1 + 16], a2 = L1T[w][g1 + 32], a3 = L1T[w][g1 + 48];
        u64 b0 = L2T[w][g2], b1 = L2T[w][g2 + 16], b2 = L2T[w][g2 + 32], b3 = L2T[w][g2 + 48];
        p[0][0] += __popcll(a0 ^ b0); p[0][1] += __popcll(a0 ^ b1);
        p[0][2] += __popcll(a0 ^ b2); p[0][3] += __popcll(a0 ^ b3);
        p[1][0] += __popcll(a1 ^ b0); p[1][1] += __popcll(a1 ^ b1);
        p[1][2] += __popcll(a1 ^ b2); p[1][3] += __popcll(a1 ^ b3);
        p[2][0] += __popcll(a2 ^ b0); p[2][1] += __popcll(a2 ^ b1);
        p[2][2] += __popcll(a2 ^ b2); p[2][3] += __popcll(a2 ^ b3);
        p[3][0] += __popcll(a3 ^ b0); p[3][1] += __popcll(a3 ^ b1);
        p[3][2] += __popcll(a3 ^ b2); p[3][3] += __popcll(a3 ^ b3);
    }
    #pragma unroll
    for (int i = 0; i < 4; i++) {
        int d1 = t1 * 64 + g1 + 16 * i;
        #pragma unroll
        for (int j = 0; j < 4; j++) {
            int d2 = t2 * 64 + g2 + 16 * j;
            g_G[((size_t)(f * D_ + d1)) * D_ + d2] = (f16)(M_ - 2 * p[i][j]);
        }
    }
    if (t1 == t2) return;
    __syncthreads();
    f16* Lt = (f16*)L1T;
    #pragma unroll
    for (int i = 0; i < 4; i++)
        #pragma unroll
        for (int j = 0; j < 4; j++)
            Lt[(g2 + 16 * j) * 72 + (g1 + 16 * i)] = (f16)(M_ - 2 * p[i][j]);
    __syncthreads();
    int r = tid >> 2, c0 = (tid & 3) * 16;
    const uint4* s = (const uint4*)&Lt[r * 72 + c0];
    uint4 v0 = s[0], v1 = s[1];
    uint4* dsto = (uint4*)&g_G[((size_t)(f * D_ + t2 * 64 + r)) * D_ + t1 * 64 + c0];
    dsto[0] = v0; dsto[1] = v1;
}

__device__ __forceinline__ u32 pairval(u32 bits, int i) {
    // two bits -> two fp16: 0x3C00 (+1) / 0xBC00 (-1)
    return 0x3C003C00u | (((bits >> i) & 1u) << 15) | (((bits >> (i + 1)) & 1u) << 31);
}

// ---- fused 15-iter loop + cleanup; single-RT ne loads, prev-in-regs ----
// 64 blocks = f(4) x dg(16); block owns d-cols [dg*64, dg*64+64) = one u64 est word.
__global__ __launch_bounds__(256) void k_loop(float* __restrict__ out) {
    int blk = blockIdx.x;
    int f = blk & 3, dg = blk >> 2;
    int tid = threadIdx.x;
    int wv = tid >> 6, lane = tid & 63;
    __shared__ u64 neL[64][17];
    __shared__ __align__(16) char ldsB[64 * 2048];  // 64 G-rows x 1024 k, XOR-swizzled
    __shared__ int red[256];
    {   // stage this block's G slice ONCE (128 KB)
        const char* gsrc = (const char*)(g_G + ((size_t)(f * D_ + dg * 64)) * D_);
        for (int i = tid; i < 8192; i += 256) {
            int row = i >> 7, col = i & 127;
            uint4 v = *(const uint4*)(gsrc + (size_t)row * 2048 + col * 16);
            *(uint4*)(ldsB + row * 2048 + ((col * 16) ^ ((row & 7) << 4))) = v;
        }
    }
    const unsigned char* neB = (const unsigned char*)neL;
    int dd = lane & 15, gg = lane >> 4;
    int aBase = (wv * 16 + dd) * 136 + gg;
    // (b,w) pairs handled by this thread in the ne phase
    int p0 = tid, p1 = 256 + tid, p2 = 512 + tid, p3 = 768 + tid;
    u64 prev[4];                                    // writer lanes' own est words
    if (dd == 0) {
        #pragma unroll
        for (int j = 0; j < 4; j++) {
            int b = wv * 16 + gg * 4 + j;
            prev[j] = g_est[0][(size_t)(b * 4 + f) * W_ + dg];
        }
    }
    int iters = 0, conv = 0;                        // live in block0's registers
    for (int t = 0; t < NITER; t++) {
        const u64* rb = g_est[t & 1];
        u64* wb = g_est[(t + 1) & 1];
        if (blk == 0) {                             // fold previous iter's convergence
            if (t > 0 && tid < NBLK) {
                const int* mp = &g_mism[t - 1][tid * FPAD];
                int v = LD_AG(&mp[0]) | LD_AG(&mp[1]) | LD_AG(&mp[2]) | LD_AG(&mp[3]);
                u64 any = __ballot(v != 0);
                if (tid == 0 && any == 0) conv = 1;
            }
            if (tid == 0 && !conv) iters++;
        }
        {   // ne phase: 16 coherent loads, ONE waitcnt (single L3 round trip)
            const char* rbB = (const char*)rb;
            const char* a0 = rbB + (size_t)(p0 >> 4) * 512 + (p0 & 15) * 8;
            const char* a1 = rbB + (size_t)(p1 >> 4) * 512 + (p1 & 15) * 8;
            const char* a2 = rbB + (size_t)(p2 >> 4) * 512 + (p2 & 15) * 8;
            const char* a3 = rbB + (size_t)(p3 >> 4) * 512 + (p3 & 15) * 8;
            u64 e00, e01, e02, e03, e10, e11, e12, e13;
            u64 e20, e21, e22, e23, e30, e31, e32, e33;
            asm volatile(
                "global_load_dwordx2 %0, %16, off sc0 sc1\n\t"
                "global_load_dwordx2 %1, %16, off offset:128 sc0 sc1\n\t"
                "global_load_dwordx2 %2, %16, off offset:256 sc0 sc1\n\t"
                "global_load_dwordx2 %3, %16, off offset:384 sc0 sc1\n\t"
                "global_load_dwordx2 %4, %17, off sc0 sc1\n\t"
                "global_load_dwordx2 %5, %17, off offset:128 sc0 sc1\n\t"
                "global_load_dwordx2 %6, %17, off offset:256 sc0 sc1\n\t"
                "global_load_dwordx2 %7, %17, off offset:384 sc0 sc1\n\t"
                "global_load_dwordx2 %8, %18, off sc0 sc1\n\t"
                "global_load_dwordx2 %9, %18, off offset:128 sc0 sc1\n\t"
                "global_load_dwordx2 %10, %18, off offset:256 sc0 sc1\n\t"
                "global_load_dwordx2 %11, %18, off offset:384 sc0 sc1\n\t"
                "global_load_dwordx2 %12, %19, off sc0 sc1\n\t"
                "global_load_dwordx2 %13, %19, off offset:128 sc0 sc1\n\t"
                "global_load_dwordx2 %14, %19, off offset:256 sc0 sc1\n\t"
                "global_load_dwordx2 %15, %19, off offset:384 sc0 sc1\n\t"
                "s_waitcnt vmcnt(0)"
                : "=&v"(e00), "=&v"(e01), "=&v"(e02), "=&v"(e03),
                  "=&v"(e10), "=&v"(e11), "=&v"(e12), "=&v"(e13),
                  "=&v"(e20), "=&v"(e21), "=&v"(e22), "=&v"(e23),
                  "=&v"(e30), "=&v"(e31), "=&v"(e32), "=&v"(e33)
                : "v"(a0), "v"(a1), "v"(a2), "v"(a3)
                : "memory");
            u64 x0 = g_inBits[(p0 >> 4) * W_ + (p0 & 15)] ^ e00 ^ e01 ^ e02 ^ e03;
            u64 x1 = g_inBits[(p1 >> 4) * W_ + (p1 & 15)] ^ e10 ^ e11 ^ e12 ^ e13;
            u64 x2 = g_inBits[(p2 >> 4) * W_ + (p2 & 15)] ^ e20 ^ e21 ^ e22 ^ e23;
            u64 x3 = g_inBits[(p3 >> 4) * W_ + (p3 & 15)] ^ e30 ^ e31 ^ e32 ^ e33;
            u64 f0 = (f == 0) ? e00 : (f == 1) ? e01 : (f == 2) ? e02 : e03;
            u64 f1 = (f == 0) ? e10 : (f == 1) ? e11 : (f == 2) ? e12 : e13;
            u64 f2 = (f == 0) ? e20 : (f == 1) ? e21 : (f == 2) ? e22 : e23;
            u64 f3 = (f == 0) ? e30 : (f == 1) ? e31 : (f == 2) ? e32 : e33;
            neL[p0 >> 4][p0 & 15] = x0 ^ f0;
            neL[p1 >> 4][p1 & 15] = x1 ^ f1;
            neL[p2 >> 4][p2 & 15] = x2 ^ f2;
            neL[p3 >> 4][p3 & 15] = x3 ^ f3;
        }
        __syncthreads();
        f32x4 acc[4][2] = {};
        #pragma unroll
        for (int c = 0; c < 32; c++) {
            u32 bits = neB[aBase + c * 4];
            f16x8 a;
            ((u32*)&a)[0] = pairval(bits, 0);
            ((u32*)&a)[1] = pairval(bits, 2);
            ((u32*)&a)[2] = pairval(bits, 4);
            ((u32*)&a)[3] = pairval(bits, 6);
            #pragma unroll
            for (int ct = 0; ct < 4; ct++) {
                int rowB = ct * 16 + dd;
                f16x8 bf = *(const f16x8*)(ldsB + rowB * 2048 +
                                           ((c * 64 + gg * 16) ^ ((rowB & 7) << 4)));
                acc[ct][c & 1] =
                    __builtin_amdgcn_mfma_f32_16x16x32_f16(a, bf, acc[ct][c & 1], 0, 0, 0);
            }
        }
        u64 msk[4][4];
        #pragma unroll
        for (int ct = 0; ct < 4; ct++)
            #pragma unroll
            for (int j = 0; j < 4; j++) {
                float v = acc[ct][0][j] + acc[ct][1][j];    // exact int
                msk[ct][j] = __ballot(v < 0.0f);
            }
        int mm = 0;
        if (dd == 0) {                              // writer lanes: one u64 per b
            #pragma unroll
            for (int j = 0; j < 4; j++) {
                int b = wv * 16 + gg * 4 + j;
                u64 nv = ((msk[0][j] >> (gg * 16)) & 0xFFFFu)
                       | (((msk[1][j] >> (gg * 16)) & 0xFFFFu) << 16)
                       | (((msk[2][j] >> (gg * 16)) & 0xFFFFu) << 32)
                       | (((msk[3][j] >> (gg * 16)) & 0xFFFFu) << 48);
                if (prev[j] != nv) mm = 1;
                prev[j] = nv;
                ST_AG(&wb[(size_t)(b * 4 + f) * W_ + dg], nv);
            }
        }
        u64 anym = __ballot(mm != 0);
        if (lane == 0 && anym)
            ST_AG(&g_mism[t][blk * FPAD + wv], 1);  // own line, no RMW
        __syncthreads();                            // vmcnt(0) drain of ALL waves' stores
        if (tid == 0)
            ST_AG(&g_done[t][blk * FPAD], 1);
        if (tid < NBLK) {                           // each thread polls one distinct line
            while (LD_AG(&g_done[t][tid * FPAD]) == 0) {}
        }
        __syncthreads();
    }
    // ---- final cleanup: 4 (b,f) tasks per block ----
    const u64* eb_g = g_est[NITER & 1];
    if (blk == 0) {
        if (tid < NBLK) {
            const int* mp = &g_mism[NITER - 1][tid * FPAD];
            int v = LD_AG(&mp[0]) | LD_AG(&mp[1]) | LD_AG(&mp[2]) | LD_AG(&mp[3]);
            u64 any = __ballot(v != 0);
            if (tid == 0) {
                if (any == 0) conv = 1;
                out[256 + 262144] = (float)iters;
                out[256 + 262144 + 1] = (float)conv;
            }
        }
    }
    for (int s = 0; s < 4; s++) {
        int task = blk * 4 + s;
        int bb = task >> 2, ff = task & 3;
        for (int j = 0; j < 4; j++) {
            int d = j * 256 + tid;
            u64 w = LD_AG(&eb_g[(size_t)(bb * 4 + ff) * W_ + (d >> 6)]);
            out[256 + ((size_t)(bb * 4 + ff)) * D_ + d] = ((w >> (d & 63)) & 1) ? -1.0f : 1.0f;
        }
        u64 eb[W_];
        #pragma unroll
        for (int w = 0; w < W_; w++) eb[w] = LD_AG(&eb_g[(size_t)(bb * 4 + ff) * W_ + w]);
        int bestKey = -1;
        for (int j = 0; j < 16; j++) {
            int m = j * 256 + tid;
            int p = 0;
            #pragma unroll
            for (int w = 0; w < W_; w++)
                p += __popcll(eb[w] ^ g_cbBits[((size_t)(ff * M_ + m)) * W_ + w]);
            int sv = D_ - 2 * p;
            int a = sv < 0 ? -sv : sv;
            int key = (a << 12) | (4095 - m);   // max |sim|, then min m
            if (key > bestKey) bestKey = key;
        }
        red[tid] = bestKey;
        __syncthreads();
        for (int off = 128; off > 0; off >>= 1) {
            if (tid < off) red[tid] = max(red[tid], red[tid + off]);
            __syncthreads();
        }
        if (tid == 0) out[bb * 4 + ff] = (float)(4095 - (red[0] & 0xFFF));
        __syncthreads();
    }
}

extern "C" void kernel_launch(void* const* d_in, const int* in_sizes, int n_in,
                              void* d_out, int out_size, void* d_ws, size_t ws_size,
                              hipStream_t stream) {
    (void)d_ws; (void)ws_size;
    const float* inp  = (const float*)d_in[0];
    const float* est0 = (const float*)d_in[1];
    const float* cb   = (const float*)d_in[2];
    float* out = (float*)d_out;

    int flagInts = 2 * NITER * NBLK * FPAD;
    int zeroBlks = (flagInts + 255) / 256;          // 120
    k_pack<<<1044 + zeroBlks, 256, 0, stream>>>(inp, est0, cb);
    k_bitT<<<256, 256, 0, stream>>>();
    k_G<<<544, 256, 0, stream>>>();
    k_loop<<<NBLK, 256, 0, stream>>>(out);
}